// Round 1
// baseline (3271.246 us; speedup 1.0000x reference)
//
#include <hip/hip_runtime.h>
#include <hip/hip_bf16.h>
#include <cstdint>
#include <cstddef>

typedef __attribute__((ext_vector_type(8))) short bf16x8;
typedef __attribute__((ext_vector_type(4))) float f32x4;
typedef __attribute__((ext_vector_type(8))) unsigned short u16x8;

__device__ __forceinline__ unsigned short f2bf(float f) {
  union { float f; unsigned u; } v; v.f = f;
  unsigned r = v.u + 0x7fffu + ((v.u >> 16) & 1u);
  return (unsigned short)(r >> 16);
}
__device__ __forceinline__ float bf2f(unsigned short u) {
  union { unsigned u; float f; } v; v.u = ((unsigned)u) << 16;
  return v.f;
}
__device__ __forceinline__ void load_lds16(const void* g, void* l) {
  __builtin_amdgcn_global_load_lds(
      (const __attribute__((address_space(1))) unsigned int*)g,
      (__attribute__((address_space(3))) unsigned int*)l, 16, 0, 0);
}

// C[M,256] = EPI(A[M,K] @ B[K,256] + bias)
// Bt: [256,K] bf16 row-major (B transposed).
// AMODE 0: A = A1 (fp32).  1: A = (1+*eps)*A1 + A2 (fp32).  2: A = Abf (bf16).
// EPI   0: Cf = val.  1: Cb = bf16(val).  2: Cb = bf16(relu(val)).
//       3: Cf = relu(val + resid)   (resid may alias Cf).
template <int AMODE, int EPI>
__global__ __launch_bounds__(512, 2) void gemm_k(
    const float* __restrict__ A1, const float* __restrict__ A2,
    const unsigned short* __restrict__ Abf, const unsigned short* __restrict__ Bt,
    const float* __restrict__ bias, const float* __restrict__ resid,
    float* __restrict__ Cf, unsigned short* __restrict__ Cb, int M, int K,
    const float* __restrict__ eps_ptr) {
  __shared__ __align__(16) unsigned short As[128 * 32];
  __shared__ __align__(16) unsigned short Bs[256 * 32];
  const int tid = threadIdx.x;
  const int wave = tid >> 6;
  const int lane = tid & 63;
  const int wr = wave >> 2;   // 0..1
  const int wc = wave & 3;    // 0..3
  const int q = lane >> 4;    // 0..3
  const int l16 = lane & 15;
  const int row0 = blockIdx.x * 128;

  float scale = 1.0f;
  if (AMODE == 1) scale = 1.0f + eps_ptr[0];

  f32x4 acc[4][4] = {};

  const int nK = K >> 5;
  for (int kt = 0; kt < nK; ++kt) {
    __syncthreads();
    // --- stage B: wave w covers rows [w*32, w*32+32), global_load_lds 16B ---
    {
      const int sub = lane >> 2;        // 0..15
      const int kb = (lane & 3) * 8;    // bf16 elem offset
#pragma unroll
      for (int i = 0; i < 2; ++i) {
        int n = wave * 32 + i * 16 + sub;
        const unsigned short* src = Bt + (size_t)n * K + kt * 32 + kb;
        load_lds16(src, &Bs[(wave * 32 + i * 16) * 32]);
      }
    }
    // --- stage A ---
    if constexpr (AMODE == 2) {
      const int sub = lane >> 2;
      const int kb = (lane & 3) * 8;
      int gr = row0 + wave * 16 + sub;
      if (gr > M - 1) gr = M - 1;
      const unsigned short* src = Abf + (size_t)gr * K + kt * 32 + kb;
      load_lds16(src, &As[(wave * 16) * 32]);
    } else {
      const int r = tid >> 2;           // 0..127
      const int kb = (tid & 3) * 8;
      int gr = row0 + r;
      if (gr > M - 1) gr = M - 1;
      const float* ap = A1 + (size_t)gr * K + kt * 32 + kb;
      float av[8];
      *(float4*)(av) = *(const float4*)ap;
      *(float4*)(av + 4) = *(const float4*)(ap + 4);
      if constexpr (AMODE == 1) {
        const float* bp = A2 + (size_t)gr * K + kt * 32 + kb;
        float bv[8];
        *(float4*)(bv) = *(const float4*)bp;
        *(float4*)(bv + 4) = *(const float4*)(bp + 4);
#pragma unroll
        for (int i = 0; i < 8; ++i) av[i] = scale * av[i] + bv[i];
      }
      u16x8 pk;
#pragma unroll
      for (int i = 0; i < 8; ++i) pk[i] = f2bf(av[i]);
      *(u16x8*)&As[r * 32 + kb] = pk;
    }
    __syncthreads();
    // --- compute: wave (wr,wc) does 64x64 via 4x4 of 16x16x32 ---
    bf16x8 af[4], bfv[4];
#pragma unroll
    for (int mi = 0; mi < 4; ++mi)
      af[mi] = *(const bf16x8*)&As[(wr * 64 + mi * 16 + l16) * 32 + q * 8];
#pragma unroll
    for (int ni = 0; ni < 4; ++ni)
      bfv[ni] = *(const bf16x8*)&Bs[(wc * 64 + ni * 16 + l16) * 32 + q * 8];
#pragma unroll
    for (int mi = 0; mi < 4; ++mi)
#pragma unroll
      for (int ni = 0; ni < 4; ++ni)
        acc[mi][ni] = __builtin_amdgcn_mfma_f32_16x16x32_bf16(af[mi], bfv[ni],
                                                              acc[mi][ni], 0, 0, 0);
  }

  // --- epilogue: C/D layout col=lane&15, row=q*4+v ---
#pragma unroll
  for (int mi = 0; mi < 4; ++mi) {
#pragma unroll
    for (int v = 0; v < 4; ++v) {
      int gr = row0 + wr * 64 + mi * 16 + q * 4 + v;
      if (gr < M) {
#pragma unroll
        for (int ni = 0; ni < 4; ++ni) {
          int c = wc * 64 + ni * 16 + l16;
          float val = acc[mi][ni][v] + bias[c];
          size_t off = (size_t)gr * 256 + c;
          if constexpr (EPI == 0) {
            Cf[off] = val;
          } else if constexpr (EPI == 1) {
            Cb[off] = f2bf(val);
          } else if constexpr (EPI == 2) {
            Cb[off] = f2bf(fmaxf(val, 0.0f));
          } else {
            Cf[off] = fmaxf(val + resid[off], 0.0f);
          }
        }
      }
    }
  }
}

// Wt[n*K+k] = bf16(W[k*N+n])
__global__ void wconv(const float* __restrict__ W, unsigned short* __restrict__ Wt,
                      int K, int N) {
  int idx = blockIdx.x * 256 + threadIdx.x;
  if (idx >= K * N) return;
  int k = idx / N, n = idx & (N - 1);  // N=256 power of two
  Wt[(size_t)n * K + k] = f2bf(W[idx]);
}

// one wave per edge: aggr[dst] += relu(h[src] + e[edge])
__global__ __launch_bounds__(256) void edge_msg(
    const float* __restrict__ h, const unsigned short* __restrict__ e,
    const int* __restrict__ src, const int* __restrict__ dst,
    float* __restrict__ aggr, int E) {
  int lane = threadIdx.x & 63;
  int eid = blockIdx.x * 4 + (threadIdx.x >> 6);
  if (eid >= E) return;
  int s = src[eid], d = dst[eid];
  int f = lane * 4;
  float4 hv = *(const float4*)(h + (size_t)s * 256 + f);
  ushort4 ev = *(const ushort4*)(e + (size_t)eid * 256 + f);
  float m0 = fmaxf(hv.x + bf2f(ev.x), 0.0f);
  float m1 = fmaxf(hv.y + bf2f(ev.y), 0.0f);
  float m2 = fmaxf(hv.z + bf2f(ev.z), 0.0f);
  float m3 = fmaxf(hv.w + bf2f(ev.w), 0.0f);
  float* ag = aggr + (size_t)d * 256 + f;
  atomicAdd(ag + 0, m0);
  atomicAdd(ag + 1, m1);
  atomicAdd(ag + 2, m2);
  atomicAdd(ag + 3, m3);
}

__global__ void seg_info(const int* __restrict__ batch, int N,
                         int* __restrict__ roots, int* __restrict__ counts) {
  int i = blockIdx.x * 256 + threadIdx.x;
  if (i >= N) return;
  int b = batch[i];
  if (i == 0 || batch[i - 1] != b) roots[b] = i;
  atomicAdd(&counts[b], 1);
}

__global__ __launch_bounds__(256) void pool_partial(
    const float* __restrict__ h, const int* __restrict__ roots,
    const int* __restrict__ counts, float* __restrict__ pooled) {
  int g = blockIdx.x, c = blockIdx.y, f = threadIdx.x;
  int r0 = roots[g], cnt = counts[g];
  int per = (cnt + gridDim.y - 1) / gridDim.y;
  int beg = c * per, end = min(beg + per, cnt);
  float s = 0.0f;
  for (int i = beg; i < end; ++i) s += h[(size_t)(r0 + i) * 256 + f];
  if (end > beg) atomicAdd(&pooled[g * 256 + f], s);
}

__global__ void pool_final(const float* __restrict__ h, const int* __restrict__ roots,
                           const int* __restrict__ counts,
                           const float* __restrict__ alpha, float* __restrict__ pooled) {
  int g = blockIdx.x, f = threadIdx.x;
  int r0 = roots[g];
  pooled[g * 256 + f] =
      pooled[g * 256 + f] / (float)counts[g] + alpha[0] * h[(size_t)r0 * 256 + f];
}

__global__ __launch_bounds__(256) void out_gemm(const float* __restrict__ pooled,
                                                const float* __restrict__ Wo,
                                                const float* __restrict__ bo,
                                                float* __restrict__ out) {
  __shared__ float row[256];
  int g = blockIdx.x, o = threadIdx.x;
  row[o] = pooled[g * 256 + o];
  __syncthreads();
  float s = bo[o];
  for (int k = 0; k < 256; ++k) s += row[k] * Wo[k * 256 + o];
  out[g * 256 + o] = s;
}

extern "C" void kernel_launch(void* const* d_in, const int* in_sizes, int n_in,
                              void* d_out, int out_size, void* d_ws, size_t ws_size,
                              hipStream_t stream) {
  const float* x = (const float*)d_in[0];
  const float* ea = (const float*)d_in[1];
  const float* Wn = (const float*)d_in[2];
  const float* bn = (const float*)d_in[3];
  const float* We = (const float*)d_in[4];
  const float* be = (const float*)d_in[5];
  const float* W11 = (const float*)d_in[6];
  const float* b11 = (const float*)d_in[7];
  const float* W12 = (const float*)d_in[8];
  const float* b12 = (const float*)d_in[9];
  const float* eps1 = (const float*)d_in[10];
  const float* W21 = (const float*)d_in[11];
  const float* b21 = (const float*)d_in[12];
  const float* W22 = (const float*)d_in[13];
  const float* b22 = (const float*)d_in[14];
  const float* eps2 = (const float*)d_in[15];
  const float* Wo = (const float*)d_in[16];
  const float* bo = (const float*)d_in[17];
  const float* alpha = (const float*)d_in[18];
  const int* ei = (const int*)d_in[19];
  const int* batch = (const int*)d_in[20];

  const int IN = 384;
  const int N = in_sizes[0] / IN;
  const int E = in_sizes[1] / IN;
  const int G = out_size / 256;
  const int* srcp = ei;
  const int* dstp = ei + E;

  char* p = (char*)d_ws;
  auto carve = [&](size_t bytes) -> void* {
    void* r = (void*)p;
    p += (bytes + 255) & ~(size_t)255;
    return r;
  };
  unsigned short* WnT = (unsigned short*)carve((size_t)256 * 384 * 2);
  unsigned short* WeT = (unsigned short*)carve((size_t)256 * 384 * 2);
  unsigned short* W11T = (unsigned short*)carve((size_t)256 * 256 * 2);
  unsigned short* W12T = (unsigned short*)carve((size_t)256 * 256 * 2);
  unsigned short* W21T = (unsigned short*)carve((size_t)256 * 256 * 2);
  unsigned short* W22T = (unsigned short*)carve((size_t)256 * 256 * 2);
  float* h = (float*)carve((size_t)N * 256 * 4);
  float* aggr = (float*)carve((size_t)N * 256 * 4);
  unsigned short* e = (unsigned short*)carve((size_t)E * 256 * 2);
  unsigned short* t = (unsigned short*)carve((size_t)N * 256 * 2);
  float* pooled = (float*)carve((size_t)G * 256 * 4);
  int* roots = (int*)carve((size_t)G * 4);
  int* counts = (int*)carve((size_t)G * 4);

  // weight transpose + bf16 convert
  wconv<<<(384 * 256 + 255) / 256, 256, 0, stream>>>(Wn, WnT, 384, 256);
  wconv<<<(384 * 256 + 255) / 256, 256, 0, stream>>>(We, WeT, 384, 256);
  wconv<<<(256 * 256 + 255) / 256, 256, 0, stream>>>(W11, W11T, 256, 256);
  wconv<<<(256 * 256 + 255) / 256, 256, 0, stream>>>(W12, W12T, 256, 256);
  wconv<<<(256 * 256 + 255) / 256, 256, 0, stream>>>(W21, W21T, 256, 256);
  wconv<<<(256 * 256 + 255) / 256, 256, 0, stream>>>(W22, W22T, 256, 256);

  const int gN = (N + 127) / 128;
  const int gE = (E + 127) / 128;

  // h = x @ Wn + bn
  gemm_k<0, 0><<<gN, 512, 0, stream>>>(x, nullptr, nullptr, WnT, bn, nullptr, h,
                                       nullptr, N, 384, nullptr);
  // e = edge_attr @ We + be   (stored bf16)
  gemm_k<0, 1><<<gE, 512, 0, stream>>>(ea, nullptr, nullptr, WeT, be, nullptr,
                                       nullptr, e, E, 384, nullptr);

  // ---- layer 1 ----
  hipMemsetAsync(aggr, 0, (size_t)N * 256 * 4, stream);
  edge_msg<<<(E + 3) / 4, 256, 0, stream>>>(h, e, srcp, dstp, aggr, E);
  gemm_k<1, 2><<<gN, 512, 0, stream>>>(h, aggr, nullptr, W11T, b11, nullptr,
                                       nullptr, t, N, 256, eps1);
  gemm_k<2, 3><<<gN, 512, 0, stream>>>(nullptr, nullptr, t, W12T, b12, h, h,
                                       nullptr, N, 256, nullptr);

  // ---- layer 2 ----
  hipMemsetAsync(aggr, 0, (size_t)N * 256 * 4, stream);
  edge_msg<<<(E + 3) / 4, 256, 0, stream>>>(h, e, srcp, dstp, aggr, E);
  gemm_k<1, 2><<<gN, 512, 0, stream>>>(h, aggr, nullptr, W21T, b21, nullptr,
                                       nullptr, t, N, 256, eps2);
  gemm_k<2, 3><<<gN, 512, 0, stream>>>(nullptr, nullptr, t, W22T, b22, h, h,
                                       nullptr, N, 256, nullptr);

  // ---- pooling + output ----
  hipMemsetAsync(counts, 0, (size_t)G * 4, stream);
  hipMemsetAsync(pooled, 0, (size_t)G * 256 * 4, stream);
  seg_info<<<(N + 255) / 256, 256, 0, stream>>>(batch, N, roots, counts);
  pool_partial<<<dim3(G, 16), 256, 0, stream>>>(h, roots, counts, pooled);
  pool_final<<<G, 256, 0, stream>>>(h, roots, counts, alpha, pooled);
  out_gemm<<<G, 256, 0, stream>>>(pooled, Wo, bo, (float*)d_out);
}

// Round 2
// 1410.580 us; speedup vs baseline: 2.3191x; 2.3191x over previous
//
#include <hip/hip_runtime.h>
#include <hip/hip_bf16.h>
#include <cstdint>
#include <cstddef>

typedef __attribute__((ext_vector_type(8))) short bf16x8;
typedef __attribute__((ext_vector_type(4))) float f32x4;
typedef __attribute__((ext_vector_type(8))) unsigned short u16x8;

__device__ __forceinline__ unsigned short f2bf(float f) {
  union { float f; unsigned u; } v; v.f = f;
  unsigned r = v.u + 0x7fffu + ((v.u >> 16) & 1u);
  return (unsigned short)(r >> 16);
}
__device__ __forceinline__ float bf2f(unsigned short u) {
  union { unsigned u; float f; } v; v.u = ((unsigned)u) << 16;
  return v.f;
}
__device__ __forceinline__ void load_lds16(const void* g, void* l) {
  __builtin_amdgcn_global_load_lds(
      (const __attribute__((address_space(1))) unsigned int*)g,
      (__attribute__((address_space(3))) unsigned int*)l, 16, 0, 0);
}

// C[M,256] = EPI(A[M,K] @ B[K,256] + bias)
// Bt: [256,K] bf16 row-major (B transposed).
// AMODE 0: A = fp32 (convert in staging).  2: A = bf16 (global_load_lds direct).
// GATHER: AMODE-0 row gr reads source row rowidx[gr].
// EPI 0: Cf = val.  1: Cb = bf16(val).  2: Cb = bf16(relu(val)).
//     3: Cf = relu(val + resid)  (resid may alias Cf).
template <int AMODE, int EPI, int GATHER>
__global__ __launch_bounds__(512, 2) void gemm_k(
    const float* __restrict__ A1, const unsigned short* __restrict__ Abf,
    const int* __restrict__ rowidx, const unsigned short* __restrict__ Bt,
    const float* __restrict__ bias, const float* __restrict__ resid,
    float* __restrict__ Cf, unsigned short* __restrict__ Cb, int M, int K) {
  __shared__ __align__(16) unsigned short As[128 * 32];
  __shared__ __align__(16) unsigned short Bs[256 * 32];
  const int tid = threadIdx.x;
  const int wave = tid >> 6;
  const int lane = tid & 63;
  const int wr = wave >> 2;   // 0..1
  const int wc = wave & 3;    // 0..3
  const int q = lane >> 4;    // 0..3
  const int l16 = lane & 15;
  const int row0 = blockIdx.x * 128;

  // staging row (K-loop invariant)
  int arow = 0;
  if constexpr (AMODE == 0) {
    int gr = row0 + (tid >> 2);
    if (gr > M - 1) gr = M - 1;
    arow = GATHER ? rowidx[gr] : gr;
  }

  f32x4 acc[4][4] = {};

  const int nK = K >> 5;
  for (int kt = 0; kt < nK; ++kt) {
    __syncthreads();
    // --- stage B: wave w covers rows [w*32, w*32+32), global_load_lds 16B ---
    {
      const int sub = lane >> 2;        // 0..15
      const int kb = (lane & 3) * 8;    // bf16 elem offset
#pragma unroll
      for (int i = 0; i < 2; ++i) {
        int n = wave * 32 + i * 16 + sub;
        const unsigned short* src = Bt + (size_t)n * K + kt * 32 + kb;
        load_lds16(src, &Bs[(wave * 32 + i * 16) * 32]);
      }
    }
    // --- stage A ---
    if constexpr (AMODE == 2) {
      const int sub = lane >> 2;
      const int kb = (lane & 3) * 8;
      int gr = row0 + wave * 16 + sub;
      if (gr > M - 1) gr = M - 1;
      const unsigned short* src = Abf + (size_t)gr * K + kt * 32 + kb;
      load_lds16(src, &As[(wave * 16) * 32]);
    } else {
      const int r = tid >> 2;           // 0..127
      const int kb = (tid & 3) * 8;
      const float* ap = A1 + (size_t)arow * K + kt * 32 + kb;
      float av[8];
      *(float4*)(av) = *(const float4*)ap;
      *(float4*)(av + 4) = *(const float4*)(ap + 4);
      u16x8 pk;
#pragma unroll
      for (int i = 0; i < 8; ++i) pk[i] = f2bf(av[i]);
      *(u16x8*)&As[r * 32 + kb] = pk;
    }
    __syncthreads();
    // --- compute: wave (wr,wc) does 64x64 via 4x4 of 16x16x32 ---
    bf16x8 af[4], bfv[4];
#pragma unroll
    for (int mi = 0; mi < 4; ++mi)
      af[mi] = *(const bf16x8*)&As[(wr * 64 + mi * 16 + l16) * 32 + q * 8];
#pragma unroll
    for (int ni = 0; ni < 4; ++ni)
      bfv[ni] = *(const bf16x8*)&Bs[(wc * 64 + ni * 16 + l16) * 32 + q * 8];
#pragma unroll
    for (int mi = 0; mi < 4; ++mi)
#pragma unroll
      for (int ni = 0; ni < 4; ++ni)
        acc[mi][ni] = __builtin_amdgcn_mfma_f32_16x16x32_bf16(af[mi], bfv[ni],
                                                              acc[mi][ni], 0, 0, 0);
  }

  // --- epilogue: C/D layout col=lane&15, row=q*4+v ---
#pragma unroll
  for (int mi = 0; mi < 4; ++mi) {
#pragma unroll
    for (int v = 0; v < 4; ++v) {
      int gr = row0 + wr * 64 + mi * 16 + q * 4 + v;
      if (gr < M) {
#pragma unroll
        for (int ni = 0; ni < 4; ++ni) {
          int c = wc * 64 + ni * 16 + l16;
          float val = acc[mi][ni][v] + bias[c];
          size_t off = (size_t)gr * 256 + c;
          if constexpr (EPI == 0) {
            Cf[off] = val;
          } else if constexpr (EPI == 1) {
            Cb[off] = f2bf(val);
          } else if constexpr (EPI == 2) {
            Cb[off] = f2bf(fmaxf(val, 0.0f));
          } else {
            Cf[off] = fmaxf(val + resid[off], 0.0f);
          }
        }
      }
    }
  }
}

// Wt[n*K+k] = bf16(W[k*N+n])
__global__ void wconv(const float* __restrict__ W, unsigned short* __restrict__ Wt,
                      int K, int N) {
  int idx = blockIdx.x * 256 + threadIdx.x;
  if (idx >= K * N) return;
  int k = idx / N, n = idx & (N - 1);  // N=256 power of two
  Wt[(size_t)n * K + k] = f2bf(W[idx]);
}

// ---------- CSR build (sort edges by dst) ----------
__global__ void hist_k(const int* __restrict__ dst, int E, int* __restrict__ deg) {
  int i = blockIdx.x * 256 + threadIdx.x;
  if (i < E) atomicAdd(&deg[dst[i]], 1);
}

__global__ __launch_bounds__(1024) void scan_k(const int* __restrict__ deg, int N,
                                               int* __restrict__ off,
                                               int* __restrict__ cursor) {
  __shared__ int wsum[16];
  __shared__ int carry_s;
  const int tid = threadIdx.x;
  const int lane = tid & 63;
  const int w = tid >> 6;
  if (tid == 0) carry_s = 0;
  __syncthreads();
  for (int base = 0; base < N; base += 1024) {
    int i = base + tid;
    int v = (i < N) ? deg[i] : 0;
    int s = v;
#pragma unroll
    for (int d = 1; d < 64; d <<= 1) {
      int t = __shfl_up(s, d);
      if (lane >= d) s += t;
    }
    if (lane == 63) wsum[w] = s;
    __syncthreads();
    if (w == 0) {
      int ws = (lane < 16) ? wsum[lane] : 0;
#pragma unroll
      for (int d = 1; d < 16; d <<= 1) {
        int t = __shfl_up(ws, d);
        if (lane >= d) ws += t;
      }
      if (lane < 16) wsum[lane] = ws;
    }
    __syncthreads();
    int carry = carry_s;
    int wprev = (w == 0) ? 0 : wsum[w - 1];
    int excl = carry + wprev + s - v;
    if (i < N) { off[i] = excl; cursor[i] = excl; }
    __syncthreads();
    if (tid == 1023) carry_s = carry + wsum[15];
    __syncthreads();
  }
  if (tid == 0) off[N] = carry_s;
}

__global__ void scatter_k(const int* __restrict__ src, const int* __restrict__ dst,
                          int E, int* __restrict__ cursor,
                          int* __restrict__ eid_at, int* __restrict__ src_sorted) {
  int i = blockIdx.x * 256 + threadIdx.x;
  if (i >= E) return;
  int d = dst[i];
  int pos = atomicAdd(&cursor[d], 1);
  eid_at[pos] = i;
  src_sorted[pos] = src[i];
}

// ---------- aggregation: one wave per node, no atomics ----------
// z[n] = bf16( (1+eps)*h[n] + sum_{j in [off[n],off[n+1])} relu(h[src_sorted[j]] + e_sorted[j]) )
__global__ __launch_bounds__(256) void node_aggr(
    const float* __restrict__ h, const unsigned short* __restrict__ e_sorted,
    const int* __restrict__ src_sorted, const int* __restrict__ off,
    const float* __restrict__ eps_ptr, unsigned short* __restrict__ z, int N) {
  const int lane = threadIdx.x & 63;
  const int node = blockIdx.x * 4 + (threadIdx.x >> 6);
  if (node >= N) return;
  const int f = lane * 4;
  const int beg = off[node];
  const int end = off[node + 1];
  float4 acc = {0.f, 0.f, 0.f, 0.f};
  for (int jb = beg; jb < end; jb += 64) {
    int n = end - jb; if (n > 64) n = 64;
    int sv = (jb + lane < end) ? src_sorted[jb + lane] : 0;
    for (int jj = 0; jj < n; ++jj) {
      int s = __shfl(sv, jj);
      float4 hv = *(const float4*)(h + (size_t)s * 256 + f);
      ushort4 ev = *(const ushort4*)(e_sorted + (size_t)(jb + jj) * 256 + f);
      acc.x += fmaxf(hv.x + bf2f(ev.x), 0.0f);
      acc.y += fmaxf(hv.y + bf2f(ev.y), 0.0f);
      acc.z += fmaxf(hv.z + bf2f(ev.z), 0.0f);
      acc.w += fmaxf(hv.w + bf2f(ev.w), 0.0f);
    }
  }
  const float sc = 1.0f + eps_ptr[0];
  float4 hd = *(const float4*)(h + (size_t)node * 256 + f);
  ushort4 zo;
  zo.x = f2bf(sc * hd.x + acc.x);
  zo.y = f2bf(sc * hd.y + acc.y);
  zo.z = f2bf(sc * hd.z + acc.z);
  zo.w = f2bf(sc * hd.w + acc.w);
  *(ushort4*)((unsigned short*)z + (size_t)node * 256 + f) = zo;
}

// ---------- pooling ----------
__global__ void seg_info(const int* __restrict__ batch, int N,
                         int* __restrict__ roots, int* __restrict__ counts) {
  int i = blockIdx.x * 256 + threadIdx.x;
  if (i >= N) return;
  int b = batch[i];
  if (i == 0 || batch[i - 1] != b) roots[b] = i;
  atomicAdd(&counts[b], 1);
}

__global__ __launch_bounds__(256) void pool_partial(
    const float* __restrict__ h, const int* __restrict__ roots,
    const int* __restrict__ counts, float* __restrict__ pooled) {
  int g = blockIdx.x, c = blockIdx.y, f = threadIdx.x;
  int r0 = roots[g], cnt = counts[g];
  int per = (cnt + gridDim.y - 1) / gridDim.y;
  int beg = c * per, end = min(beg + per, cnt);
  float s = 0.0f;
  for (int i = beg; i < end; ++i) s += h[(size_t)(r0 + i) * 256 + f];
  if (end > beg) atomicAdd(&pooled[g * 256 + f], s);
}

__global__ void pool_final(const float* __restrict__ h, const int* __restrict__ roots,
                           const int* __restrict__ counts,
                           const float* __restrict__ alpha, float* __restrict__ pooled) {
  int g = blockIdx.x, f = threadIdx.x;
  int r0 = roots[g];
  pooled[g * 256 + f] =
      pooled[g * 256 + f] / (float)counts[g] + alpha[0] * h[(size_t)r0 * 256 + f];
}

__global__ __launch_bounds__(256) void out_gemm(const float* __restrict__ pooled,
                                                const float* __restrict__ Wo,
                                                const float* __restrict__ bo,
                                                float* __restrict__ out) {
  __shared__ float row[256];
  int g = blockIdx.x, o = threadIdx.x;
  row[o] = pooled[g * 256 + o];
  __syncthreads();
  float s = bo[o];
  for (int k = 0; k < 256; ++k) s += row[k] * Wo[k * 256 + o];
  out[g * 256 + o] = s;
}

extern "C" void kernel_launch(void* const* d_in, const int* in_sizes, int n_in,
                              void* d_out, int out_size, void* d_ws, size_t ws_size,
                              hipStream_t stream) {
  const float* x = (const float*)d_in[0];
  const float* ea = (const float*)d_in[1];
  const float* Wn = (const float*)d_in[2];
  const float* bn = (const float*)d_in[3];
  const float* We = (const float*)d_in[4];
  const float* be = (const float*)d_in[5];
  const float* W11 = (const float*)d_in[6];
  const float* b11 = (const float*)d_in[7];
  const float* W12 = (const float*)d_in[8];
  const float* b12 = (const float*)d_in[9];
  const float* eps1 = (const float*)d_in[10];
  const float* W21 = (const float*)d_in[11];
  const float* b21 = (const float*)d_in[12];
  const float* W22 = (const float*)d_in[13];
  const float* b22 = (const float*)d_in[14];
  const float* eps2 = (const float*)d_in[15];
  const float* Wo = (const float*)d_in[16];
  const float* bo = (const float*)d_in[17];
  const float* alpha = (const float*)d_in[18];
  const int* ei = (const int*)d_in[19];
  const int* batch = (const int*)d_in[20];

  const int IN = 384;
  const int N = in_sizes[0] / IN;
  const int E = in_sizes[1] / IN;
  const int G = out_size / 256;
  const int* srcp = ei;
  const int* dstp = ei + E;

  char* p = (char*)d_ws;
  auto carve = [&](size_t bytes) -> void* {
    void* r = (void*)p;
    p += (bytes + 255) & ~(size_t)255;
    return r;
  };
  unsigned short* WnT = (unsigned short*)carve((size_t)256 * 384 * 2);
  unsigned short* WeT = (unsigned short*)carve((size_t)256 * 384 * 2);
  unsigned short* W11T = (unsigned short*)carve((size_t)256 * 256 * 2);
  unsigned short* W12T = (unsigned short*)carve((size_t)256 * 256 * 2);
  unsigned short* W21T = (unsigned short*)carve((size_t)256 * 256 * 2);
  unsigned short* W22T = (unsigned short*)carve((size_t)256 * 256 * 2);
  float* h = (float*)carve((size_t)N * 256 * 4);
  unsigned short* e_sorted = (unsigned short*)carve((size_t)E * 256 * 2);
  unsigned short* z = (unsigned short*)carve((size_t)N * 256 * 2);
  unsigned short* t = (unsigned short*)carve((size_t)N * 256 * 2);
  int* deg = (int*)carve((size_t)N * 4);
  int* off = (int*)carve((size_t)(N + 1) * 4);
  int* cursor = (int*)carve((size_t)N * 4);
  int* eid_at = (int*)carve((size_t)E * 4);
  int* src_sorted = (int*)carve((size_t)E * 4);
  float* pooled = (float*)carve((size_t)G * 256 * 4);
  int* roots = (int*)carve((size_t)G * 4);
  int* counts = (int*)carve((size_t)G * 4);

  // ---- CSR build ----
  hipMemsetAsync(deg, 0, (size_t)N * 4, stream);
  hist_k<<<(E + 255) / 256, 256, 0, stream>>>(dstp, E, deg);
  scan_k<<<1, 1024, 0, stream>>>(deg, N, off, cursor);
  scatter_k<<<(E + 255) / 256, 256, 0, stream>>>(srcp, dstp, E, cursor, eid_at,
                                                 src_sorted);

  // ---- weight transpose + bf16 convert ----
  wconv<<<(384 * 256 + 255) / 256, 256, 0, stream>>>(Wn, WnT, 384, 256);
  wconv<<<(384 * 256 + 255) / 256, 256, 0, stream>>>(We, WeT, 384, 256);
  wconv<<<(256 * 256 + 255) / 256, 256, 0, stream>>>(W11, W11T, 256, 256);
  wconv<<<(256 * 256 + 255) / 256, 256, 0, stream>>>(W12, W12T, 256, 256);
  wconv<<<(256 * 256 + 255) / 256, 256, 0, stream>>>(W21, W21T, 256, 256);
  wconv<<<(256 * 256 + 255) / 256, 256, 0, stream>>>(W22, W22T, 256, 256);

  const int gN = (N + 127) / 128;
  const int gE = (E + 127) / 128;

  // h = x @ Wn + bn
  gemm_k<0, 0, 0><<<gN, 512, 0, stream>>>(x, nullptr, nullptr, WnT, bn, nullptr,
                                          h, nullptr, N, 384);
  // e_sorted[j] = bf16(edge_attr[eid_at[j]] @ We + be)  — written in dst-sorted order
  gemm_k<0, 1, 1><<<gE, 512, 0, stream>>>(ea, nullptr, eid_at, WeT, be, nullptr,
                                          nullptr, e_sorted, E, 384);

  // ---- layer 1 ----
  node_aggr<<<(N + 3) / 4, 256, 0, stream>>>(h, e_sorted, src_sorted, off, eps1,
                                             z, N);
  gemm_k<2, 2, 0><<<gN, 512, 0, stream>>>(nullptr, z, nullptr, W11T, b11,
                                          nullptr, nullptr, t, N, 256);
  gemm_k<2, 3, 0><<<gN, 512, 0, stream>>>(nullptr, t, nullptr, W12T, b12, h, h,
                                          nullptr, N, 256);

  // ---- layer 2 ----
  node_aggr<<<(N + 3) / 4, 256, 0, stream>>>(h, e_sorted, src_sorted, off, eps2,
                                             z, N);
  gemm_k<2, 2, 0><<<gN, 512, 0, stream>>>(nullptr, z, nullptr, W21T, b21,
                                          nullptr, nullptr, t, N, 256);
  gemm_k<2, 3, 0><<<gN, 512, 0, stream>>>(nullptr, t, nullptr, W22T, b22, h, h,
                                          nullptr, N, 256);

  // ---- pooling + output ----
  hipMemsetAsync(counts, 0, (size_t)G * 4, stream);
  hipMemsetAsync(pooled, 0, (size_t)G * 256 * 4, stream);
  seg_info<<<(N + 255) / 256, 256, 0, stream>>>(batch, N, roots, counts);
  pool_partial<<<dim3(G, 16), 256, 0, stream>>>(h, roots, counts, pooled);
  pool_final<<<G, 256, 0, stream>>>(h, roots, counts, alpha, pooled);
  out_gemm<<<G, 256, 0, stream>>>(pooled, Wo, bo, (float*)d_out);
}